// Round 13
// baseline (93.460 us; speedup 1.0000x reference)
//
#include <hip/hip_runtime.h>
#include <stdint.h>

typedef unsigned int uint;
typedef unsigned short ushort;

#define NPTS  262144
#define PLANE_T_ELEMS (65536 * 32)
#define PLANE_T_BYTES ((size_t)PLANE_T_ELEMS * 2)
#define WS_PLANES_BYTES ((size_t)3 * PLANE_T_ELEMS * 2)   // 12582912
#define WS_GRB_OFF  WS_PLANES_BYTES
#define WS_NEEDED   (WS_PLANES_BYTES + (size_t)32768 * 2)

typedef __attribute__((ext_vector_type(8))) short bf16x8;   // 8 bf16 = 4 VGPR
typedef __attribute__((ext_vector_type(4))) float f32x4;

__device__ __forceinline__ ushort f2bf(float f) {
  union { float f; uint u; } v; v.f = f;
  uint r = v.u + 0x7fffu + ((v.u >> 16) & 1u);   // RNE
  return (ushort)(r >> 16);
}
__device__ __forceinline__ float bf_lo(uint u) {
  union { uint u; float f; } v; v.u = u << 16; return v.f;
}
__device__ __forceinline__ float bf_hi(uint u) {
  union { uint u; float f; } v; v.u = u & 0xffff0000u; return v.f;
}
__device__ __forceinline__ float b2f(ushort u) {
  union { uint u; float f; } v; v.u = (uint)u << 16; return v.f;
}
__device__ __forceinline__ uint cvtpk_bf16(float lo, float hi) {
  uint r;
  asm("v_cvt_pk_bf16_f32 %0, %1, %2" : "=v"(r) : "v"(lo), "v"(hi));
  return r;
}

// ---------- prep kernels (unchanged, verified R2-R12) ----------

__global__ __launch_bounds__(256) void transpose_planes_k(
    const float* __restrict__ pxy, const float* __restrict__ pyz,
    const float* __restrict__ pxz, ushort* __restrict__ out) {
  int plane = blockIdx.x >> 8;
  int h = blockIdx.x & 255;
  const float* src = (plane == 0) ? pxy : (plane == 1) ? pyz : pxz;
  int w = threadIdx.x;
  int p = (h << 8) + w;
  uint vals[16];
#pragma unroll
  for (int c = 0; c < 32; c += 2) {
    float f0 = src[(size_t)c * 65536 + p];
    float f1 = src[(size_t)(c + 1) * 65536 + p];
    vals[c >> 1] = (uint)f2bf(f0) | ((uint)f2bf(f1) << 16);
  }
  uint4* d4 = (uint4*)(out + (size_t)plane * PLANE_T_ELEMS + (size_t)p * 32);
#pragma unroll
  for (int i = 0; i < 4; ++i)
    d4[i] = make_uint4(vals[4 * i], vals[4 * i + 1], vals[4 * i + 2], vals[4 * i + 3]);
}

// G[x][y][z] -> fragment-ordered bf16 table (verified):
// byte off = (y*2+xh)*1024 + l*16 + j*2  ->  G[x= xh*16+(l&15)][y][z= (l>>4)*8+j]
__global__ __launch_bounds__(256) void prep_grb_k(const float* __restrict__ g,
                                                  ushort* __restrict__ grb) {
  int e = blockIdx.x * 256 + threadIdx.x;   // 0..32767
  int j = e & 7;
  int l = (e >> 3) & 63;
  int xh = (e >> 9) & 1;
  int y = e >> 10;
  int x = xh * 16 + (l & 15);
  int z = ((l >> 4) << 3) + j;
  grb[e] = f2bf(g[x * 1024 + y * 32 + z]);
}

// ---------- bilinear sampler (verified R2-R12, verbatim) ----------
template <bool BIG, class F>
__device__ __forceinline__ void sample_plane(const ushort* __restrict__ bt,
                                             const float* __restrict__ bf,
                                             float gw, float gh, F store) {
  float fx = (gw + 1.0f) * 0.5f * 255.0f;
  float fy = (gh + 1.0f) * 0.5f * 255.0f;
  float fx0 = floorf(fx), fy0 = floorf(fy);
  float wx1 = fx - fx0, wy1 = fy - fy0;
  float wx0 = 1.0f - wx1, wy0 = 1.0f - wy1;
  int ix0 = (int)fx0, iy0 = (int)fy0;
  int ix1 = ix0 + 1, iy1 = iy0 + 1;
  bool vx0 = (ix0 >= 0) & (ix0 < 256);
  bool vx1 = (ix1 >= 0) & (ix1 < 256);
  bool vy0 = (iy0 >= 0) & (iy0 < 256);
  bool vy1 = (iy1 >= 0) & (iy1 < 256);
  float w00 = (vx0 & vy0) ? wx0 * wy0 : 0.0f;
  float w10 = (vx1 & vy0) ? wx1 * wy0 : 0.0f;
  float w01 = (vx0 & vy1) ? wx0 * wy1 : 0.0f;
  float w11 = (vx1 & vy1) ? wx1 * wy1 : 0.0f;
  int cx0 = min(max(ix0, 0), 255), cx1 = min(max(ix1, 0), 255);
  int cy0 = min(max(iy0, 0), 255), cy1 = min(max(iy1, 0), 255);
  if (BIG) {
    uint o00 = (uint)(((cy0 << 8) + cx0) << 6);
    uint o10 = (uint)(((cy0 << 8) + cx1) << 6);
    uint o01 = (uint)(((cy1 << 8) + cx0) << 6);
    uint o11 = (uint)(((cy1 << 8) + cx1) << 6);
    const char* base = (const char*)bt;
#pragma unroll
    for (int cc = 0; cc < 32; cc += 8) {
      uint4 a = *(const uint4*)(base + o00 + cc * 2);
      uint4 b = *(const uint4*)(base + o10 + cc * 2);
      uint4 c = *(const uint4*)(base + o01 + cc * 2);
      uint4 d = *(const uint4*)(base + o11 + cc * 2);
      const uint* pa = (const uint*)&a; const uint* pb = (const uint*)&b;
      const uint* pc = (const uint*)&c; const uint* pd = (const uint*)&d;
#pragma unroll
      for (int j = 0; j < 4; ++j) {
        float v0 = w00 * bf_lo(pa[j]) + w10 * bf_lo(pb[j]) +
                   w01 * bf_lo(pc[j]) + w11 * bf_lo(pd[j]);
        float v1 = w00 * bf_hi(pa[j]) + w10 * bf_hi(pb[j]) +
                   w01 * bf_hi(pc[j]) + w11 * bf_hi(pd[j]);
        store(cc + 2 * j, v0);
        store(cc + 2 * j + 1, v1);
      }
    }
  } else {
    int o00 = (cy0 << 8) + cx0, o10 = (cy0 << 8) + cx1;
    int o01 = (cy1 << 8) + cx0, o11 = (cy1 << 8) + cx1;
#pragma unroll
    for (int c = 0; c < 32; ++c) {
      const float* base = bf + (size_t)c * 65536;
      float v = w00 * base[o00] + w10 * base[o10] + w01 * base[o01] + w11 * base[o11];
      store(c, v);
    }
  }
}

// ---------- MFMA main kernel: 384 threads, 1 plane-sample/thread, 128 pts/block ----------
__global__ __launch_bounds__(384, 2) void tucker_mfma_k(
    const float* __restrict__ coords,
    const ushort* __restrict__ planes_t,
    const ushort* __restrict__ grb,
    float* __restrict__ out) {
  __shared__ ushort xy_s[128][36];   // 72B rows (R4/R7-proven)
  __shared__ ushort xz_s[128][40];   // 80B rows, 16B-aligned b128 slots
  __shared__ ushort yz_s[128][36];   // 72B rows
  __shared__ float part_s[4][128];   // per-wave y-partials

  int tid = threadIdx.x;
  int l = tid & 63;
  int wv = tid >> 6;                 // compute-wave id (0..3 used in main loop)
  int s = l & 15;
  int kb = l >> 4;

  // ---- sampling: each thread samples exactly ONE plane for its point ----
  int q = tid & 127;                 // point row in LDS (384 = 3 x 128)
  int plane = tid >> 7;              // 0: xy, 1: yz, 2: xz (wave-uniform)
  int p = blockIdx.x * 128 + q;
  float c0c = coords[3 * p + 0] * (1.0f / 1.3f);
  float c1c = coords[3 * p + 1] * (1.0f / 1.3f);
  float c2c = coords[3 * p + 2] * (1.0f / 1.3f);

  {
    uint buf[16];
    auto pack = [&](int c, float v) {
      ushort h = f2bf(v);
      if (c & 1) buf[c >> 1] |= ((uint)h << 16);
      else buf[c >> 1] = (uint)h;
    };
    if (plane == 0) {
      // xy: W<-x(c0), H<-y(c1)
      sample_plane<true>(planes_t, nullptr, c0c, c1c, pack);
      uint2* r2 = (uint2*)xy_s[q];
#pragma unroll
      for (int i = 0; i < 8; ++i) r2[i] = make_uint2(buf[2 * i], buf[2 * i + 1]);
    } else if (plane == 1) {
      // yz: W<-y(c1), H<-z(c2)
      sample_plane<true>(planes_t + (size_t)PLANE_T_ELEMS, nullptr, c1c, c2c, pack);
      uint2* r2 = (uint2*)yz_s[q];
#pragma unroll
      for (int i = 0; i < 8; ++i) r2[i] = make_uint2(buf[2 * i], buf[2 * i + 1]);
    } else {
      // xz: W<-x(c0), H<-z(c2)
      sample_plane<true>(planes_t + (size_t)2 * PLANE_T_ELEMS, nullptr, c0c, c2c, pack);
      uint4* r4 = (uint4*)xz_s[q];
#pragma unroll
      for (int i = 0; i < 4; ++i)
        r4[i] = make_uint4(buf[4 * i], buf[4 * i + 1], buf[4 * i + 2], buf[4 * i + 3]);
    }
  }

  // ---- compute waves preload their 16 G-fragments (latency hides under barrier) ----
  bf16x8 greg[8][2];
  if (tid < 256) {
    const char* gb = (const char*)grb;
    uint lbase = (uint)l * 16;
#pragma unroll
    for (int yl = 0; yl < 8; ++yl) {
#pragma unroll
      for (int h = 0; h < 2; ++h)
        greg[yl][h] =
            *(const bf16x8*)(gb + (uint)((wv * 8 + yl) * 2048 + h * 1024) + lbase);
    }
#pragma unroll
    for (int yl = 0; yl < 8; ++yl) {
      asm volatile("" : "+v"(greg[yl][0]));
      asm volatile("" : "+v"(greg[yl][1]));
    }
  }
  __syncthreads();

  // ---- main loop: waves 0-3 only; LDS + register operands, 8 point-tiles ----
  if (tid < 256) {
    f32x4 zero = {0.f, 0.f, 0.f, 0.f};
#pragma unroll 2
    for (int t = 0; t < 8; ++t) {
      int pt = t * 16 + s;
      uint4 xzu = *(const uint4*)(&xz_s[pt][0] + kb * 8);
      float xzf[8] = {bf_lo(xzu.x), bf_hi(xzu.x), bf_lo(xzu.y), bf_hi(xzu.y),
                      bf_lo(xzu.z), bf_hi(xzu.z), bf_lo(xzu.w), bf_hi(xzu.w)};
      const ushort* yr = yz_s[pt];
      uint yp0 = *(const uint*)(yr + wv * 8 + 0);
      uint yp1 = *(const uint*)(yr + wv * 8 + 2);
      uint yp2 = *(const uint*)(yr + wv * 8 + 4);
      uint yp3 = *(const uint*)(yr + wv * 8 + 6);
      uint yp[4] = {yp0, yp1, yp2, yp3};

      f32x4 acc0 = zero, acc1 = zero;
#pragma unroll
      for (int qq = 0; qq < 4; ++qq) {
#pragma unroll
        for (int par = 0; par < 2; ++par) {
          float yv = par ? bf_hi(yp[qq]) : bf_lo(yp[qq]);
          union { uint u[4]; bf16x8 v; } a;
          a.u[0] = cvtpk_bf16(yv * xzf[0], yv * xzf[1]);
          a.u[1] = cvtpk_bf16(yv * xzf[2], yv * xzf[3]);
          a.u[2] = cvtpk_bf16(yv * xzf[4], yv * xzf[5]);
          a.u[3] = cvtpk_bf16(yv * xzf[6], yv * xzf[7]);
          acc0 = __builtin_amdgcn_mfma_f32_16x16x32_bf16(a.v, greg[2 * qq + par][0],
                                                         acc0, 0, 0, 0);
          acc1 = __builtin_amdgcn_mfma_f32_16x16x32_bf16(a.v, greg[2 * qq + par][1],
                                                         acc1, 0, 0, 0);
        }
      }

      // per-tile epilogue: D[row=kb*4+r = point][col=s = x]; dot with xy, reduce over x
#pragma unroll
      for (int r = 0; r < 4; ++r) {
        int pm = t * 16 + kb * 4 + r;
        float v = acc0[r] * b2f(xy_s[pm][s]) + acc1[r] * b2f(xy_s[pm][16 + s]);
        v += __shfl_xor(v, 1, 64);
        v += __shfl_xor(v, 2, 64);
        v += __shfl_xor(v, 4, 64);
        v += __shfl_xor(v, 8, 64);
        if (s == 0) part_s[wv][pm] = v;
      }
    }
  }
  __syncthreads();

  // cross-wave sum of y-partials (linear, exact partition of y=0..31)
  if (tid < 128)
    out[blockIdx.x * 128 + tid] =
        part_s[0][tid] + part_s[1][tid] + part_s[2][tid] + part_s[3][tid];
}

// ---------- fallback (no workspace): slow-but-correct ----------
__global__ __launch_bounds__(256) void tucker_small_k(
    const float* __restrict__ coords,
    const float* __restrict__ pxy, const float* __restrict__ pyz,
    const float* __restrict__ pxz, const float* __restrict__ g,
    float* __restrict__ out) {
  __shared__ float s_yz[256 * 33];
  int tid = threadIdx.x;
  int p = blockIdx.x * 256 + tid;
  float c0 = coords[3 * p + 0] / 1.3f;
  float c1 = coords[3 * p + 1] / 1.3f;
  float c2 = coords[3 * p + 2] / 1.3f;
  float xy[32], xz[32];
  float* yzrow = &s_yz[tid * 33];
  sample_plane<false>(nullptr, pxy, c0, c1, [&](int c, float v) { xy[c] = v; });
  sample_plane<false>(nullptr, pyz, c1, c2, [&](int c, float v) { yzrow[c] = v; });
  sample_plane<false>(nullptr, pxz, c0, c2, [&](int c, float v) { xz[c] = v; });
  float acc = 0.0f;
  for (int y = 0; y < 32; ++y) {
    float yzv = yzrow[y];
    float accy = 0.0f;
#pragma unroll
    for (int z = 0; z < 32; ++z) {
      float t0 = 0.f, t1 = 0.f, t2 = 0.f, t3 = 0.f;
#pragma unroll
      for (int x = 0; x < 32; x += 4) {
        t0 = fmaf(g[(x + 0) * 1024 + y * 32 + z], xy[x + 0], t0);
        t1 = fmaf(g[(x + 1) * 1024 + y * 32 + z], xy[x + 1], t1);
        t2 = fmaf(g[(x + 2) * 1024 + y * 32 + z], xy[x + 2], t2);
        t3 = fmaf(g[(x + 3) * 1024 + y * 32 + z], xy[x + 3], t3);
      }
      accy = fmaf((t0 + t1) + (t2 + t3), xz[z], accy);
    }
    acc = fmaf(accy, yzv, acc);
  }
  out[p] = acc;
}

extern "C" void kernel_launch(void* const* d_in, const int* in_sizes, int n_in,
                              void* d_out, int out_size, void* d_ws, size_t ws_size,
                              hipStream_t stream) {
  const float* coords = (const float*)d_in[0];
  const float* pxy = (const float*)d_in[1];
  const float* pyz = (const float*)d_in[2];
  const float* pxz = (const float*)d_in[3];
  const float* g   = (const float*)d_in[4];
  float* out = (float*)d_out;

  if (ws_size >= WS_NEEDED) {
    ushort* planes_t = (ushort*)d_ws;
    ushort* grb = (ushort*)((char*)d_ws + WS_GRB_OFF);
    hipLaunchKernelGGL(transpose_planes_k, dim3(768), dim3(256), 0, stream,
                       pxy, pyz, pxz, planes_t);
    hipLaunchKernelGGL(prep_grb_k, dim3(128), dim3(256), 0, stream, g, grb);
    hipLaunchKernelGGL(tucker_mfma_k, dim3(NPTS / 128), dim3(384), 0, stream,
                       coords, planes_t, grb, out);
  } else {
    hipLaunchKernelGGL(tucker_small_k, dim3(NPTS / 256), dim3(256), 0, stream,
                       coords, pxy, pyz, pxz, g, out);
  }
}

// Round 14
// 60.208 us; speedup vs baseline: 1.5523x; 1.5523x over previous
//
#include <hip/hip_runtime.h>
#include <stdint.h>

typedef unsigned int uint;
typedef unsigned short ushort;

#define NPTS  262144
#define PLANE_T_ELEMS (65536 * 32)
#define PLANE_T_BYTES ((size_t)PLANE_T_ELEMS * 2)
#define WS_PLANES_BYTES ((size_t)3 * PLANE_T_ELEMS * 2)   // 12582912
#define WS_GRB_OFF  WS_PLANES_BYTES
#define WS_NEEDED   (WS_PLANES_BYTES + (size_t)32768 * 2)

typedef __attribute__((ext_vector_type(8))) short bf16x8;   // 8 bf16 = 4 VGPR
typedef __attribute__((ext_vector_type(4))) float f32x4;
typedef __attribute__((ext_vector_type(2))) float f32x2;

__device__ __forceinline__ ushort f2bf(float f) {
  union { float f; uint u; } v; v.f = f;
  uint r = v.u + 0x7fffu + ((v.u >> 16) & 1u);   // RNE
  return (ushort)(r >> 16);
}
__device__ __forceinline__ float bf_lo(uint u) {
  union { uint u; float f; } v; v.u = u << 16; return v.f;
}
__device__ __forceinline__ float bf_hi(uint u) {
  union { uint u; float f; } v; v.u = u & 0xffff0000u; return v.f;
}
__device__ __forceinline__ float b2f(ushort u) {
  union { uint u; float f; } v; v.u = (uint)u << 16; return v.f;
}

// ---------- prep kernels (unchanged, verified R2-R12) ----------

__global__ __launch_bounds__(256) void transpose_planes_k(
    const float* __restrict__ pxy, const float* __restrict__ pyz,
    const float* __restrict__ pxz, ushort* __restrict__ out) {
  int plane = blockIdx.x >> 8;
  int h = blockIdx.x & 255;
  const float* src = (plane == 0) ? pxy : (plane == 1) ? pyz : pxz;
  int w = threadIdx.x;
  int p = (h << 8) + w;
  uint vals[16];
#pragma unroll
  for (int c = 0; c < 32; c += 2) {
    float f0 = src[(size_t)c * 65536 + p];
    float f1 = src[(size_t)(c + 1) * 65536 + p];
    vals[c >> 1] = (uint)f2bf(f0) | ((uint)f2bf(f1) << 16);
  }
  uint4* d4 = (uint4*)(out + (size_t)plane * PLANE_T_ELEMS + (size_t)p * 32);
#pragma unroll
  for (int i = 0; i < 4; ++i)
    d4[i] = make_uint4(vals[4 * i], vals[4 * i + 1], vals[4 * i + 2], vals[4 * i + 3]);
}

// G[x][y][z] -> fragment-ordered bf16 table (verified):
// byte off = (y*2+xh)*1024 + l*16 + j*2  ->  G[x= xh*16+(l&15)][y][z= (l>>4)*8+j]
__global__ __launch_bounds__(256) void prep_grb_k(const float* __restrict__ g,
                                                  ushort* __restrict__ grb) {
  int e = blockIdx.x * 256 + threadIdx.x;   // 0..32767
  int j = e & 7;
  int l = (e >> 3) & 63;
  int xh = (e >> 9) & 1;
  int y = e >> 10;
  int x = xh * 16 + (l & 15);
  int z = ((l >> 4) << 3) + j;
  grb[e] = f2bf(g[x * 1024 + y * 32 + z]);
}

// ---------- bilinear sampler (verified R2-R12, verbatim) ----------
template <bool BIG, class F>
__device__ __forceinline__ void sample_plane(const ushort* __restrict__ bt,
                                             const float* __restrict__ bf,
                                             float gw, float gh, F store) {
  float fx = (gw + 1.0f) * 0.5f * 255.0f;
  float fy = (gh + 1.0f) * 0.5f * 255.0f;
  float fx0 = floorf(fx), fy0 = floorf(fy);
  float wx1 = fx - fx0, wy1 = fy - fy0;
  float wx0 = 1.0f - wx1, wy0 = 1.0f - wy1;
  int ix0 = (int)fx0, iy0 = (int)fy0;
  int ix1 = ix0 + 1, iy1 = iy0 + 1;
  bool vx0 = (ix0 >= 0) & (ix0 < 256);
  bool vx1 = (ix1 >= 0) & (ix1 < 256);
  bool vy0 = (iy0 >= 0) & (iy0 < 256);
  bool vy1 = (iy1 >= 0) & (iy1 < 256);
  float w00 = (vx0 & vy0) ? wx0 * wy0 : 0.0f;
  float w10 = (vx1 & vy0) ? wx1 * wy0 : 0.0f;
  float w01 = (vx0 & vy1) ? wx0 * wy1 : 0.0f;
  float w11 = (vx1 & vy1) ? wx1 * wy1 : 0.0f;
  int cx0 = min(max(ix0, 0), 255), cx1 = min(max(ix1, 0), 255);
  int cy0 = min(max(iy0, 0), 255), cy1 = min(max(iy1, 0), 255);
  if (BIG) {
    uint o00 = (uint)(((cy0 << 8) + cx0) << 6);
    uint o10 = (uint)(((cy0 << 8) + cx1) << 6);
    uint o01 = (uint)(((cy1 << 8) + cx0) << 6);
    uint o11 = (uint)(((cy1 << 8) + cx1) << 6);
    const char* base = (const char*)bt;
#pragma unroll
    for (int cc = 0; cc < 32; cc += 8) {
      uint4 a = *(const uint4*)(base + o00 + cc * 2);
      uint4 b = *(const uint4*)(base + o10 + cc * 2);
      uint4 c = *(const uint4*)(base + o01 + cc * 2);
      uint4 d = *(const uint4*)(base + o11 + cc * 2);
      const uint* pa = (const uint*)&a; const uint* pb = (const uint*)&b;
      const uint* pc = (const uint*)&c; const uint* pd = (const uint*)&d;
#pragma unroll
      for (int j = 0; j < 4; ++j) {
        float v0 = w00 * bf_lo(pa[j]) + w10 * bf_lo(pb[j]) +
                   w01 * bf_lo(pc[j]) + w11 * bf_lo(pd[j]);
        float v1 = w00 * bf_hi(pa[j]) + w10 * bf_hi(pb[j]) +
                   w01 * bf_hi(pc[j]) + w11 * bf_hi(pd[j]);
        store(cc + 2 * j, v0);
        store(cc + 2 * j + 1, v1);
      }
    }
  } else {
    int o00 = (cy0 << 8) + cx0, o10 = (cy0 << 8) + cx1;
    int o01 = (cy1 << 8) + cx0, o11 = (cy1 << 8) + cx1;
#pragma unroll
    for (int c = 0; c < 32; ++c) {
      const float* base = bf + (size_t)c * 65536;
      float v = w00 * base[o00] + w10 * base[o10] + w01 * base[o01] + w11 * base[o11];
      store(c, v);
    }
  }
}

// ---------- MFMA main kernel: R12 structure + R4 operand scheme (no A-build) ----------
__global__ __launch_bounds__(256, 4) void tucker_mfma_k(
    const float* __restrict__ coords,
    const ushort* __restrict__ planes_t,
    const ushort* __restrict__ grb,
    float* __restrict__ out) {
  __shared__ ushort xy_s[128][36];   // 72B rows (R4/R7-proven)
  __shared__ ushort xz_s[128][40];   // 80B rows, 16B-aligned b128 slots
  __shared__ ushort yz_s[128][36];   // 72B rows
  __shared__ float part_s[4][128];   // per-wave y-partials

  int tid = threadIdx.x;
  int l = tid & 63;
  int wv = tid >> 6;       // wave owns y = wv*8 .. wv*8+7
  int s = l & 15;
  int kb = l >> 4;

  // ---- sampling: R12 code paths, split by half (wave-uniform) ----
  int q = tid & 127;                 // point row in LDS
  int p = blockIdx.x * 128 + q;
  float c0c = coords[3 * p + 0] * (1.0f / 1.3f);
  float c1c = coords[3 * p + 1] * (1.0f / 1.3f);
  float c2c = coords[3 * p + 2] * (1.0f / 1.3f);

  if (tid < 128) {
    uint buf[16];
    auto pack = [&](int c, float v) {
      ushort h = f2bf(v);
      if (c & 1) buf[c >> 1] |= ((uint)h << 16);
      else buf[c >> 1] = (uint)h;
    };
    // xy: W<-x(c0), H<-y(c1)
    sample_plane<true>(planes_t, nullptr, c0c, c1c, pack);
    uint2* r2 = (uint2*)xy_s[q];
#pragma unroll
    for (int i = 0; i < 8; ++i) r2[i] = make_uint2(buf[2 * i], buf[2 * i + 1]);
    // yz: W<-y(c1), H<-z(c2)
    sample_plane<true>(planes_t + (size_t)PLANE_T_ELEMS, nullptr, c1c, c2c, pack);
    r2 = (uint2*)yz_s[q];
#pragma unroll
    for (int i = 0; i < 8; ++i) r2[i] = make_uint2(buf[2 * i], buf[2 * i + 1]);
  } else {
    uint buf[16];
    auto pack = [&](int c, float v) {
      ushort h = f2bf(v);
      if (c & 1) buf[c >> 1] |= ((uint)h << 16);
      else buf[c >> 1] = (uint)h;
    };
    // xz: W<-x(c0), H<-z(c2)
    sample_plane<true>(planes_t + (size_t)2 * PLANE_T_ELEMS, nullptr, c0c, c2c, pack);
    uint4* r4 = (uint4*)xz_s[q];
#pragma unroll
    for (int i = 0; i < 4; ++i)
      r4[i] = make_uint4(buf[4 * i], buf[4 * i + 1], buf[4 * i + 2], buf[4 * i + 3]);
  }

  // ---- pin this wave's 16 G-fragments in VGPRs (asm keep-alive) ----
  const char* gb = (const char*)grb;
  uint lbase = (uint)l * 16;
  bf16x8 greg[8][2];
#pragma unroll
  for (int yl = 0; yl < 8; ++yl) {
#pragma unroll
    for (int h = 0; h < 2; ++h)
      greg[yl][h] =
          *(const bf16x8*)(gb + (uint)((wv * 8 + yl) * 2048 + h * 1024) + lbase);
  }
#pragma unroll
  for (int yl = 0; yl < 8; ++yl) {
    asm volatile("" : "+v"(greg[yl][0]));
    asm volatile("" : "+v"(greg[yl][1]));
  }
  __syncthreads();

  // ---- main loop: d = mfma(G, xz); acc += yz[y]*d  (R4-verified scheme) ----
  f32x4 zero = {0.f, 0.f, 0.f, 0.f};
#pragma unroll 2
  for (int t = 0; t < 8; ++t) {
    int pt = t * 16 + s;
    union BF { uint4 u; bf16x8 v; } bfrag;       // B = raw xz bf16 (zero prep)
    bfrag.u = *(const uint4*)(&xz_s[pt][0] + kb * 8);
    const ushort* yr = yz_s[pt];
    uint yp[4];
    yp[0] = *(const uint*)(yr + wv * 8 + 0);
    yp[1] = *(const uint*)(yr + wv * 8 + 2);
    yp[2] = *(const uint*)(yr + wv * 8 + 4);
    yp[3] = *(const uint*)(yr + wv * 8 + 6);

    // acc pairs: [0],[1] -> x = kb*4+{0,1},{2,3}; [2],[3] -> x = 16+kb*4+...
    f32x2 acc0 = {0.f, 0.f}, acc1 = {0.f, 0.f};
    f32x2 acc2 = {0.f, 0.f}, acc3 = {0.f, 0.f};
#pragma unroll
    for (int qq = 0; qq < 4; ++qq) {
#pragma unroll
      for (int par = 0; par < 2; ++par) {
        float yv = par ? bf_hi(yp[qq]) : bf_lo(yp[qq]);
        union D { f32x4 v; f32x2 h[2]; } d0, d1;
        d0.v = __builtin_amdgcn_mfma_f32_16x16x32_bf16(greg[2 * qq + par][0],
                                                       bfrag.v, zero, 0, 0, 0);
        d1.v = __builtin_amdgcn_mfma_f32_16x16x32_bf16(greg[2 * qq + par][1],
                                                       bfrag.v, zero, 0, 0, 0);
        f32x2 yvv = {yv, yv};
        acc0 += d0.h[0] * yvv;
        acc1 += d0.h[1] * yvv;
        acc2 += d1.h[0] * yvv;
        acc3 += d1.h[1] * yvv;
      }
    }

    // epilogue (R4-verified D-layout: row=x=kb*4+r, col=point=s):
    // v = sum over lane's 8 x's of xy[pt][x] * W[x, pt]; reduce over kb groups
    const uint* xyr = (const uint*)xy_s[pt];
    uint q0 = xyr[kb * 2], q1 = xyr[kb * 2 + 1];
    uint q2 = xyr[8 + kb * 2], q3 = xyr[8 + kb * 2 + 1];
    float v = acc0[0] * bf_lo(q0) + acc0[1] * bf_hi(q0)
            + acc1[0] * bf_lo(q1) + acc1[1] * bf_hi(q1)
            + acc2[0] * bf_lo(q2) + acc2[1] * bf_hi(q2)
            + acc3[0] * bf_lo(q3) + acc3[1] * bf_hi(q3);
    v += __shfl_xor(v, 16, 64);
    v += __shfl_xor(v, 32, 64);
    if (l < 16) part_s[wv][pt] = v;   // kb==0 lanes hold pt = t*16+s
  }
  __syncthreads();

  // cross-wave sum of y-partials (linear, exact partition of y=0..31)
  if (tid < 128)
    out[blockIdx.x * 128 + tid] =
        part_s[0][tid] + part_s[1][tid] + part_s[2][tid] + part_s[3][tid];
}

// ---------- fallback (no workspace): slow-but-correct ----------
__global__ __launch_bounds__(256) void tucker_small_k(
    const float* __restrict__ coords,
    const float* __restrict__ pxy, const float* __restrict__ pyz,
    const float* __restrict__ pxz, const float* __restrict__ g,
    float* __restrict__ out) {
  __shared__ float s_yz[256 * 33];
  int tid = threadIdx.x;
  int p = blockIdx.x * 256 + tid;
  float c0 = coords[3 * p + 0] / 1.3f;
  float c1 = coords[3 * p + 1] / 1.3f;
  float c2 = coords[3 * p + 2] / 1.3f;
  float xy[32], xz[32];
  float* yzrow = &s_yz[tid * 33];
  sample_plane<false>(nullptr, pxy, c0, c1, [&](int c, float v) { xy[c] = v; });
  sample_plane<false>(nullptr, pyz, c1, c2, [&](int c, float v) { yzrow[c] = v; });
  sample_plane<false>(nullptr, pxz, c0, c2, [&](int c, float v) { xz[c] = v; });
  float acc = 0.0f;
  for (int y = 0; y < 32; ++y) {
    float yzv = yzrow[y];
    float accy = 0.0f;
#pragma unroll
    for (int z = 0; z < 32; ++z) {
      float t0 = 0.f, t1 = 0.f, t2 = 0.f, t3 = 0.f;
#pragma unroll
      for (int x = 0; x < 32; x += 4) {
        t0 = fmaf(g[(x + 0) * 1024 + y * 32 + z], xy[x + 0], t0);
        t1 = fmaf(g[(x + 1) * 1024 + y * 32 + z], xy[x + 1], t1);
        t2 = fmaf(g[(x + 2) * 1024 + y * 32 + z], xy[x + 2], t2);
        t3 = fmaf(g[(x + 3) * 1024 + y * 32 + z], xy[x + 3], t3);
      }
      accy = fmaf((t0 + t1) + (t2 + t3), xz[z], accy);
    }
    acc = fmaf(accy, yzv, acc);
  }
  out[p] = acc;
}

extern "C" void kernel_launch(void* const* d_in, const int* in_sizes, int n_in,
                              void* d_out, int out_size, void* d_ws, size_t ws_size,
                              hipStream_t stream) {
  const float* coords = (const float*)d_in[0];
  const float* pxy = (const float*)d_in[1];
  const float* pyz = (const float*)d_in[2];
  const float* pxz = (const float*)d_in[3];
  const float* g   = (const float*)d_in[4];
  float* out = (float*)d_out;

  if (ws_size >= WS_NEEDED) {
    ushort* planes_t = (ushort*)d_ws;
    ushort* grb = (ushort*)((char*)d_ws + WS_GRB_OFF);
    hipLaunchKernelGGL(transpose_planes_k, dim3(768), dim3(256), 0, stream,
                       pxy, pyz, pxz, planes_t);
    hipLaunchKernelGGL(prep_grb_k, dim3(128), dim3(256), 0, stream, g, grb);
    hipLaunchKernelGGL(tucker_mfma_k, dim3(NPTS / 128), dim3(256), 0, stream,
                       coords, planes_t, grb, out);
  } else {
    hipLaunchKernelGGL(tucker_small_k, dim3(NPTS / 256), dim3(256), 0, stream,
                       coords, pxy, pyz, pxz, g, out);
  }
}